// Round 2
// baseline (682235.742 us; speedup 1.0000x reference)
//
#include <hip/hip_runtime.h>
#include <stdint.h>
#include <stddef.h>

// PowerLawLayer RNN, MI355X persistent-kernel, R6.
//
// R4: 19.7 ms; latency-bound (VALUBusy 11.6%, HBM 1.3%), 19.2 us/step vs
//     0.96 us/step FMA floor.
// R5: flag-store barrier (no RMW, 1 acquire/step): NEUTRAL (20.4 ms, all
//     counters identical) => LLC RMW contention was NOT the bottleneck.
// R6 theory: the cost is agent scope itself: every h load/store and flag op
//     is sc1 (LLC round-trip ~600-900cy) and each step pays buffer_inv +
//     buffer_wbl2 per WG (32x per XCD). Evidence: FETCH=127MB ~ 2x the x
//     array (L2 keeps being invalidated under read-only x) and WRITE=1.86GB
//     ~ 14x out[] (wbl2 flushes partial 64B lines every step).
//     The 8 batch-groups are independent; a group's 32 peers only talk to
//     each other. If a group's peers all sit on ONE XCD, its L2 is their
//     coherence point: sc0 loads (L1 bypass) + write-through stores suffice,
//     no inv/wb. We do NOT assume the bid->XCD mapping: read HW_REG_XCC_ID,
//     publish via an agent-scope startup barrier, and pick:
//       mode 1: bid&7 grouping is XCD-uniform  (round-robin dispatch)
//       mode 2: bid>>5 grouping is XCD-uniform (chunked dispatch)
//       mode 0: neither -> R5 agent-scope fallback (correct anywhere).
//
// Workspace: hbuf[2][64][512] f32 + flags[8*32] + xcdmap[256] + ctr0
//            = 262144 + 1024 + 1024 + 4 B.

#define Hh   512
#define Tt   1024
#define Bb   64
#define II   256
#define EPSc 0.001f
#define PV   0.2f
#define NPEER 32

__global__ __launch_bounds__(1024) void plr_init(float* hbuf, unsigned* flags) {
  int idx = blockIdx.x * blockDim.x + threadIdx.x;
  if (idx < Bb * Hh) hbuf[idx] = 0.0f;          // h(0) = 0 in buffer 0
  if (idx < 8 * NPEER + 257) flags[idx] = 0u;   // flags + xcdmap + ctr0
}

// ---- sc0 (L1-bypass, XCD-L2-coherent) access helpers ------------------
__device__ __forceinline__ void st_sc0_f32(float* p, float v) {
  asm volatile("global_store_dword %0, %1, off sc0" :: "v"(p), "v"(v) : "memory");
}
__device__ __forceinline__ void st_sc0_u32(unsigned* p, unsigned v) {
  asm volatile("global_store_dword %0, %1, off sc0" :: "v"(p), "v"(v) : "memory");
}
__device__ __forceinline__ unsigned ld_sc0_u32(const unsigned* p) {
  unsigned v;  // waitcnt INSIDE the asm: consumer is register-only (rule #18)
  asm volatile("global_load_dword %0, %1, off sc0\n\ts_waitcnt vmcnt(0)"
               : "=v"(v) : "v"(p) : "memory");
  return v;
}

template <bool LOCAL>
__device__ __forceinline__ void plr_loop(
    const float* __restrict__ x, const float* __restrict__ bias,
    float* __restrict__ out, float* hbuf, unsigned* flags,
    float* h_tile, float* x_tile, float* part,
    const float (&whh)[3][16], const float (&wih)[3][8], int g, int s) {
  const int tid = threadIdx.x;
  const int w   = tid >> 6;
  const int l   = tid & 63;
  const int jj  = l & 15;
  const int kl  = (l >> 4) & 3;
  const int kc  = (w << 2) | kl;
  const int j0  = s * 16;
  const int b0  = g * 8;
  (void)jj; (void)kl;

  // ---- updater state (threads 0..127: br = tid>>4, jr = tid&15) -------
  float c_st = 0.0f, k_st = -1.0f;
  float bia0 = 0.f, bia1 = 0.f, bia2 = 0.f;
  if (tid < 128) {
    const int jr = tid & 15;
    bia0 = bias[0 * Hh + j0 + jr];
    bia1 = bias[1 * Hh + j0 + jr];
    bia2 = bias[2 * Hh + j0 + jr];
  }

  // ---- prologue: stage x(0) -------------------------------------------
  {
    const int bl = tid >> 6, k4 = (tid & 63) * 4;
    *(float4*)(x_tile + bl * II + k4) =
        *(const float4*)(x + ((size_t)(b0 + bl) * Tt + 0) * II + k4);
  }

  bool broken = false;  // bounded-spin escape (never taken when co-resident)

  for (int t = 0; t < Tt; ++t) {
    // ---- stage h(t): LOCAL = sc0 (XCD L2), else agent (LLC) ------------
    {
      const float* hb = hbuf + (size_t)(t & 1) * Bb * Hh + (size_t)b0 * Hh;
      if (LOCAL) {
        float hv[8];
#pragma unroll
        for (int i = 0; i < 8; ++i)
          asm volatile("global_load_dword %0, %1, off sc0"
                       : "=v"(hv[i]) : "v"(hb + (size_t)i * Hh + tid));
        asm volatile("s_waitcnt vmcnt(0)" ::: "memory");
#pragma unroll
        for (int i = 0; i < 8; ++i) h_tile[i * Hh + tid] = hv[i];
      } else {
#pragma unroll
        for (int i = 0; i < 8; ++i)
          h_tile[i * Hh + tid] = __hip_atomic_load(
              hb + i * Hh + tid, __ATOMIC_RELAXED, __HIP_MEMORY_SCOPE_AGENT);
      }
    }
    __syncthreads();  // (A) h_tile + x_tile ready

    // ---- gemv: 576 FMA/thread in 2 passes of 4 batches -----------------
    const float* xt = x_tile + (t & 1) * 8 * II;
#pragma unroll
    for (int pass = 0; pass < 2; ++pass) {
      float acc[3][4];
#pragma unroll
      for (int b4 = 0; b4 < 4; ++b4) {
        const int bl = pass * 4 + b4;
        const float4* h4 = (const float4*)(h_tile + bl * Hh) + kc * 4;
        const float4* x4 = (const float4*)(xt + bl * II) + kc * 2;
        float a0 = 0.f, a1 = 0.f, a2 = 0.f;
#pragma unroll
        for (int i = 0; i < 4; ++i) {
          float4 hv = h4[i];
          a0 = fmaf(whh[0][4*i+0], hv.x, a0); a0 = fmaf(whh[0][4*i+1], hv.y, a0);
          a0 = fmaf(whh[0][4*i+2], hv.z, a0); a0 = fmaf(whh[0][4*i+3], hv.w, a0);
          a1 = fmaf(whh[1][4*i+0], hv.x, a1); a1 = fmaf(whh[1][4*i+1], hv.y, a1);
          a1 = fmaf(whh[1][4*i+2], hv.z, a1); a1 = fmaf(whh[1][4*i+3], hv.w, a1);
          a2 = fmaf(whh[2][4*i+0], hv.x, a2); a2 = fmaf(whh[2][4*i+1], hv.y, a2);
          a2 = fmaf(whh[2][4*i+2], hv.z, a2); a2 = fmaf(whh[2][4*i+3], hv.w, a2);
        }
#pragma unroll
        for (int i = 0; i < 2; ++i) {
          float4 xv = x4[i];
          a0 = fmaf(wih[0][4*i+0], xv.x, a0); a0 = fmaf(wih[0][4*i+1], xv.y, a0);
          a0 = fmaf(wih[0][4*i+2], xv.z, a0); a0 = fmaf(wih[0][4*i+3], xv.w, a0);
          a1 = fmaf(wih[1][4*i+0], xv.x, a1); a1 = fmaf(wih[1][4*i+1], xv.y, a1);
          a1 = fmaf(wih[1][4*i+2], xv.z, a1); a1 = fmaf(wih[1][4*i+3], xv.w, a1);
          a2 = fmaf(wih[2][4*i+0], xv.x, a2); a2 = fmaf(wih[2][4*i+1], xv.y, a2);
          a2 = fmaf(wih[2][4*i+2], xv.z, a2); a2 = fmaf(wih[2][4*i+3], xv.w, a2);
        }
        acc[0][b4] = a0; acc[1][b4] = a1; acc[2][b4] = a2;
      }
      // reduce the 4 kl sub-chunks in-register, one masked store per combo
#pragma unroll
      for (int gi = 0; gi < 3; ++gi)
#pragma unroll
        for (int b4 = 0; b4 < 4; ++b4) {
          float v = acc[gi][b4];
          v += __shfl_xor(v, 16, 64);
          v += __shfl_xor(v, 32, 64);
          if (l < 16)
            part[((gi * 8 + pass * 4 + b4) * 8 + w) * 17 + (l & 15)] = v;
        }
    }

    // ---- stage x(t+1) during the gap (independent of h exchange) -------
    if (t + 1 < Tt) {
      const int bl = tid >> 6, k4 = (tid & 63) * 4;
      *(float4*)(x_tile + ((t + 1) & 1) * 8 * II + bl * II + k4) =
          *(const float4*)(x + ((size_t)(b0 + bl) * Tt + (t + 1)) * II + k4);
    }
    __syncthreads();  // (B) partials visible

    // ---- reduce + elementwise + h store (threads 0..127) ---------------
    float hn = 0.f, cn = 0.f, kn = 0.f;
    if (tid < 128) {
      const int jr = tid & 15, br = tid >> 4;
      float s0 = bia0, s1 = bia1, s2 = bia2;
#pragma unroll
      for (int ww = 0; ww < 8; ++ww) {
        s0 += part[((0 * 8 + br) * 8 + ww) * 17 + jr];
        s1 += part[((1 * 8 + br) * 8 + ww) * 17 + jr];
        s2 += part[((2 * 8 + br) * 8 + ww) * 17 + jr];
      }
      const float tf = (float)t;
      const float r  = 1.0f / (1.0f + __expf(-s0));
      const float o  = 1.0f / (1.0f + __expf(-s1));
      const float gg = 1.0f - 2.0f / (1.0f + __expf(2.0f * s2));
      kn = r * (tf - EPSc) + (1.0f - r) * k_st;
      const float d  = tf - kn;
      const float f  = __expf(PV * __logf((d + EPSc) / (d + 1.0f)));
      cn = f * c_st + (1.0f - f) * gg;
      hn = o * (1.0f - 2.0f / (1.0f + __expf(2.0f * cn)));
      c_st = cn; k_st = kn;
      float* hp = hbuf + (size_t)((t + 1) & 1) * Bb * Hh +
                  (size_t)(b0 + br) * Hh + j0 + jr;
      if (LOCAL)
        st_sc0_f32(hp, hn);  // write-through to XCD L2
      else
        __hip_atomic_store(hp, hn, __ATOMIC_RELAXED, __HIP_MEMORY_SCOPE_AGENT);
    }
    __syncthreads();  // (C) drains h stores (vmcnt) before the signal

    // ---- signal: per-WG flag store (own word; one line per group) ------
    if (t < Tt - 1 && tid == 0) {
      unsigned* fp = flags + g * NPEER + s;
      if (LOCAL)
        st_sc0_u32(fp, (unsigned)(t + 1));  // L2 is the coherence point
      else
        __hip_atomic_store(fp, (unsigned)(t + 1), __ATOMIC_RELEASE,
                           __HIP_MEMORY_SCOPE_AGENT);
    }

    // ---- out[] store (off the critical path, after the signal) ---------
    if (tid < 128) {
      const int jr = tid & 15, br = tid >> 4;
      const int b = b0 + br, j = j0 + jr;
      out[((size_t)b * Tt + t) * Hh + j] = hn;
      if (t == Tt - 1) {
        const size_t base = (size_t)Bb * Tt * Hh;
        out[base + 0 * Bb * Hh + (size_t)b * Hh + j] = hn;  // h_f
        out[base + 1 * Bb * Hh + (size_t)b * Hh + j] = cn;  // c_f
        out[base + 2 * Bb * Hh + (size_t)b * Hh + j] = kn;  // k_f
      }
    }

    // ---- 32-peer wait: wave 0 polls all 32 flags ------------------------
    if (t < Tt - 1) {
      if (tid < 64 && !broken) {
        const unsigned target = (unsigned)(t + 1);
        const unsigned* fl = flags + g * NPEER + (tid & (NPEER - 1));
        int it = 0;
        for (;;) {
          unsigned v = LOCAL ? ld_sc0_u32(fl)
                             : __hip_atomic_load(fl, __ATOMIC_RELAXED,
                                                 __HIP_MEMORY_SCOPE_AGENT);
          if (__all((int)(v >= target))) break;
          __builtin_amdgcn_s_sleep(1);
          if (++it > (1 << 22)) { broken = true; break; }
        }
        if (!LOCAL)  // pair with peers' releases (one inv/step, not per poll)
          (void)__hip_atomic_load(fl, __ATOMIC_ACQUIRE,
                                  __HIP_MEMORY_SCOPE_AGENT);
      }
      __syncthreads();  // (D) all threads ordered behind wave 0's wait
    }
  }
}

__global__ __launch_bounds__(512, 3)
void plr_main(
    const float* __restrict__ x,    // [B, T, I]
    const float* __restrict__ Wih,  // [3H, I]
    const float* __restrict__ Whh,  // [3H, H]
    const float* __restrict__ bias, // [3H]
    float* __restrict__ out,        // [B,T,H] ++ h_f ++ c_f ++ k_f
    float* hbuf,                    // [2][B][H]
    unsigned* flags)                // [8*32] flags ++ [256] xcdmap ++ ctr0
{
  __shared__ float h_tile[8 * Hh];        // [bl][k]      16 KB
  __shared__ float x_tile[2 * 8 * II];    // [buf][bl][k] 16 KB
  __shared__ float part[3264];            // ((gi*8+bl)*8+w)*17 + jj  12.8 KB
  __shared__ unsigned sxc[257];           // startup: xcd map + mode

  const int tid = threadIdx.x;
  const int bid = blockIdx.x;

  // ---- startup: measure the actual WG->XCD placement (once) -----------
  unsigned myxcd;
  asm volatile("s_getreg_b32 %0, hwreg(HW_REG_XCC_ID)" : "=s"(myxcd));
  unsigned* xcdmap = flags + 8 * NPEER;   // [256]
  unsigned* ctr0   = xcdmap + 256;        // [1]
  if (tid == 0) {
    __hip_atomic_store(xcdmap + bid, myxcd, __ATOMIC_RELAXED,
                       __HIP_MEMORY_SCOPE_AGENT);
    __hip_atomic_fetch_add(ctr0, 1u, __ATOMIC_ACQ_REL,
                           __HIP_MEMORY_SCOPE_AGENT);
    int it = 0;
    while (__hip_atomic_load(ctr0, __ATOMIC_ACQUIRE,
                             __HIP_MEMORY_SCOPE_AGENT) < 256u) {
      __builtin_amdgcn_s_sleep(8);
      if (++it > (1 << 22)) break;  // bounded (co-residency assumed, as R4/R5)
    }
  }
  __syncthreads();
  if (tid < 256)
    sxc[tid] = __hip_atomic_load(xcdmap + tid, __ATOMIC_RELAXED,
                                 __HIP_MEMORY_SCOPE_AGENT);
  __syncthreads();
  if (tid == 0) {
    bool pa = true, pb = true;   // round-robin / chunked XCD-uniformity
    for (int gg = 0; gg < 8; ++gg) {
      unsigned ra = sxc[gg], rb = sxc[gg * 32];
      for (int p = 0; p < 32; ++p) {
        pa = pa && (sxc[p * 8 + gg] == ra);
        pb = pb && (sxc[gg * 32 + p] == rb);
      }
    }
    sxc[256] = pa ? 1u : (pb ? 2u : 0u);
  }
  __syncthreads();
  const unsigned mode = sxc[256];
  int g, s;
  if (mode == 2u) { g = bid >> 5; s = bid & 31; }   // chunked dispatch
  else            { g = bid & 7;  s = bid >> 3; }   // round-robin (or fallback)

  // ---- one-time: weights into registers (72 floats/thread) ------------
  const int w  = tid >> 6;
  const int l  = tid & 63;
  const int jj = l & 15;
  const int kc = (w << 2) | ((l >> 4) & 3);
  const int j0 = s * 16;
  float whh[3][16];
  float wih[3][8];
#pragma unroll
  for (int gi = 0; gi < 3; ++gi) {
    const int row = gi * Hh + j0 + jj;
    const float4* ph = (const float4*)(Whh + (size_t)row * Hh + kc * 16);
#pragma unroll
    for (int i = 0; i < 4; ++i) {
      float4 v = ph[i];
      whh[gi][4*i+0] = v.x; whh[gi][4*i+1] = v.y;
      whh[gi][4*i+2] = v.z; whh[gi][4*i+3] = v.w;
    }
    const float4* pi = (const float4*)(Wih + (size_t)row * II + kc * 8);
#pragma unroll
    for (int i = 0; i < 2; ++i) {
      float4 v = pi[i];
      wih[gi][4*i+0] = v.x; wih[gi][4*i+1] = v.y;
      wih[gi][4*i+2] = v.z; wih[gi][4*i+3] = v.w;
    }
  }

  if (mode != 0u)
    plr_loop<true >(x, bias, out, hbuf, flags, h_tile, x_tile, part,
                    whh, wih, g, s);
  else
    plr_loop<false>(x, bias, out, hbuf, flags, h_tile, x_tile, part,
                    whh, wih, g, s);
}

extern "C" void kernel_launch(void* const* d_in, const int* in_sizes, int n_in,
                              void* d_out, int out_size, void* d_ws, size_t ws_size,
                              hipStream_t stream) {
  const float* x    = (const float*)d_in[0];
  const float* Wih  = (const float*)d_in[1];
  const float* Whh  = (const float*)d_in[2];
  const float* bias = (const float*)d_in[3];
  float* out = (float*)d_out;

  float*    hbuf  = (float*)d_ws;                                 // 2*64*512 f32
  unsigned* flags = (unsigned*)((char*)d_ws + 2 * Bb * Hh * sizeof(float));

  plr_init<<<32, 1024, 0, stream>>>(hbuf, flags);
  plr_main<<<256, 512, 0, stream>>>(x, Wih, Whh, bias, out, hbuf, flags);
}

// Round 3
// 5780.764 us; speedup vs baseline: 118.0183x; 118.0183x over previous
//
#include <hip/hip_runtime.h>
#include <stdint.h>
#include <stddef.h>

// PowerLawLayer RNN, MI355X persistent-kernel, R7.
//
// R4: 19.7 ms; latency-bound (VALUBusy 11.6%, HBM 1.3%); 19.2 us/step vs
//     0.96 us/step FMA floor.
// R5: flag-store barrier (no RMW, 1 acquire/step): NEUTRAL => barrier
//     mechanics are not the cost.
// R6: sc0 "XCD-local" exchange: CATASTROPHIC (682 ms). sc0 gives NO
//     cross-CU visibility on gfx950 (remote L1s hold stale lines until
//     capacity eviction). Agent scope (sc1 -> IC) is the only usable
//     cross-CU coherence point. Reverted.
// R7: fuse data+signal. Each h element is an 8-byte atom
//     (tag<<32 | f32bits) written with ONE relaxed agent store; consumers
//     poll the data itself (tag==t) - no flags, no acquire/buffer_inv, no
//     (C) vmcnt drain, no (D) barrier. Chain/step = store -> visibility ->
//     load, the minimum for cross-CU dataflow. Ping-pong buffers make the
//     overwrite race impossible by data dependence: producer reaching its
//     step-t store has consumed all peers' step-t inputs, proving every
//     peer finished its step-(t-1) reads of the slot being overwritten.
//     x-part gemv (192 FMA/thread, h-independent) overlaps the poll.
//
// Workspace: hbuf2[2][64][512] u64 = 524,288 B.

#define Hh   512
#define Tt   1024
#define Bb   64
#define II   256
#define EPSc 0.001f
#define PV   0.2f

typedef unsigned long long u64;

__global__ __launch_bounds__(1024) void plr_init(u64* hbuf2) {
  // 2*Bb*Hh = 65536 slots; 32768 threads: 2 each.
  // buf0: tag 0 == "h(0) ready" (h bits = 0.0f). buf1: tag 0 != 1 => stale.
  int idx = blockIdx.x * blockDim.x + threadIdx.x;
  hbuf2[idx] = 0ull;
  hbuf2[idx + 32768] = 0ull;
}

__global__ __launch_bounds__(512, 2)  // cap 256 VGPR; grid==#CUs so
void plr_main(                        // occupancy is 1 WG/CU regardless
    const float* __restrict__ x,    // [B, T, I]
    const float* __restrict__ Wih,  // [3H, I]
    const float* __restrict__ Whh,  // [3H, H]
    const float* __restrict__ bias, // [3H]
    float* __restrict__ out,        // [B,T,H] ++ h_f ++ c_f ++ k_f
    u64* hbuf2)                     // [2][B][H] tagged h atoms
{
  __shared__ float h_tile[8 * Hh];        // [bl][k]      16 KB
  __shared__ float x_tile[2 * 8 * II];    // [buf][bl][k] 16 KB
  __shared__ float part[3264];            // ((gi*8+bl)*8+w)*17 + jj  12.8 KB

  const int tid = threadIdx.x;
  const int w   = tid >> 6;          // wave 0..7
  const int l   = tid & 63;
  const int jj  = l & 15;            // hidden offset within slice
  const int kc  = (w << 2) | ((l >> 4) & 3);  // k-chunk 0..31
  const int bid = blockIdx.x;
  const int g   = bid & 7;           // batch group
  const int s   = bid >> 3;          // hidden slice 0..31
  const int j0  = s * 16;
  const int b0  = g * 8;

  // ---- one-time: weights into registers (72 floats/thread) ------------
  float whh[3][16];
  float wih[3][8];
#pragma unroll
  for (int gi = 0; gi < 3; ++gi) {
    const int row = gi * Hh + j0 + jj;
    const float4* ph = (const float4*)(Whh + (size_t)row * Hh + kc * 16);
#pragma unroll
    for (int i = 0; i < 4; ++i) {
      float4 v = ph[i];
      whh[gi][4*i+0] = v.x; whh[gi][4*i+1] = v.y;
      whh[gi][4*i+2] = v.z; whh[gi][4*i+3] = v.w;
    }
    const float4* pi = (const float4*)(Wih + (size_t)row * II + kc * 8);
#pragma unroll
    for (int i = 0; i < 2; ++i) {
      float4 v = pi[i];
      wih[gi][4*i+0] = v.x; wih[gi][4*i+1] = v.y;
      wih[gi][4*i+2] = v.z; wih[gi][4*i+3] = v.w;
    }
  }

  // ---- updater state (threads 0..127: br = tid>>4, jr = tid&15) -------
  float c_st = 0.0f, k_st = -1.0f;
  float bia0 = 0.f, bia1 = 0.f, bia2 = 0.f;
  if (tid < 128) {
    const int jr = tid & 15;
    bia0 = bias[0 * Hh + j0 + jr];
    bia1 = bias[1 * Hh + j0 + jr];
    bia2 = bias[2 * Hh + j0 + jr];
  }

  // ---- prologue: stage x(0) -------------------------------------------
  {
    const int bl = tid >> 6, k4 = (tid & 63) * 4;
    *(float4*)(x_tile + bl * II + k4) =
        *(const float4*)(x + ((size_t)(b0 + bl) * Tt + 0) * II + k4);
  }
  __syncthreads();  // x(0) visible to all waves' x-part at t=0

  bool broken = false;  // bounded-spin escape (never taken when co-resident)

  for (int t = 0; t < Tt; ++t) {
    // ---- issue tagged h loads: slot (bl=i, k=tid), tag must equal t ----
    const u64* hb = hbuf2 + (size_t)(t & 1) * Bb * Hh + (size_t)b0 * Hh;
    u64 got[8];
#pragma unroll
    for (int i = 0; i < 8; ++i)
      got[i] = __hip_atomic_load(hb + (size_t)i * Hh + tid, __ATOMIC_RELAXED,
                                 __HIP_MEMORY_SCOPE_AGENT);

    // ---- overlap: x-part gemv (h-independent) for all 8 batches --------
    const float* xt = x_tile + (t & 1) * 8 * II;
    float xacc[3][8];
#pragma unroll
    for (int bl = 0; bl < 8; ++bl) {
      const float4* x4 = (const float4*)(xt + bl * II) + kc * 2;
      float a0 = 0.f, a1 = 0.f, a2 = 0.f;
#pragma unroll
      for (int i = 0; i < 2; ++i) {
        float4 xv = x4[i];
        a0 = fmaf(wih[0][4*i+0], xv.x, a0); a0 = fmaf(wih[0][4*i+1], xv.y, a0);
        a0 = fmaf(wih[0][4*i+2], xv.z, a0); a0 = fmaf(wih[0][4*i+3], xv.w, a0);
        a1 = fmaf(wih[1][4*i+0], xv.x, a1); a1 = fmaf(wih[1][4*i+1], xv.y, a1);
        a1 = fmaf(wih[1][4*i+2], xv.z, a1); a1 = fmaf(wih[1][4*i+3], xv.w, a1);
        a2 = fmaf(wih[2][4*i+0], xv.x, a2); a2 = fmaf(wih[2][4*i+1], xv.y, a2);
        a2 = fmaf(wih[2][4*i+2], xv.z, a2); a2 = fmaf(wih[2][4*i+3], xv.w, a2);
      }
      xacc[0][bl] = a0; xacc[1][bl] = a1; xacc[2][bl] = a2;
    }

    // ---- retry loop: poll data until every slot carries tag t ----------
    {
      const unsigned want = (unsigned)t;
      int it = 0;
      for (;;) {
        bool ok = true;
#pragma unroll
        for (int i = 0; i < 8; ++i) ok &= ((unsigned)(got[i] >> 32) == want);
        if (__all((int)ok)) break;          // wave-coherent exit
        if (++it > (1 << 20)) { broken = true; break; }
        __builtin_amdgcn_s_sleep(1);
#pragma unroll
        for (int i = 0; i < 8; ++i)
          if ((unsigned)(got[i] >> 32) != want)
            got[i] = __hip_atomic_load(hb + (size_t)i * Hh + tid,
                                       __ATOMIC_RELAXED,
                                       __HIP_MEMORY_SCOPE_AGENT);
      }
    }

    // ---- fill h_tile (value is the low dword of the atom) --------------
#pragma unroll
    for (int i = 0; i < 8; ++i)
      h_tile[i * Hh + tid] = __uint_as_float((unsigned)got[i]);
    __syncthreads();  // (A) h_tile complete; also fences part[] reuse

    // ---- h-part gemv: 384 FMA/thread in 2 passes of 4 batches ----------
#pragma unroll
    for (int pass = 0; pass < 2; ++pass) {
      float acc[3][4];
#pragma unroll
      for (int b4 = 0; b4 < 4; ++b4) {
        const int bl = pass * 4 + b4;
        const float4* h4 = (const float4*)(h_tile + bl * Hh) + kc * 4;
        float a0 = xacc[0][bl], a1 = xacc[1][bl], a2 = xacc[2][bl];
#pragma unroll
        for (int i = 0; i < 4; ++i) {
          float4 hv = h4[i];
          a0 = fmaf(whh[0][4*i+0], hv.x, a0); a0 = fmaf(whh[0][4*i+1], hv.y, a0);
          a0 = fmaf(whh[0][4*i+2], hv.z, a0); a0 = fmaf(whh[0][4*i+3], hv.w, a0);
          a1 = fmaf(whh[1][4*i+0], hv.x, a1); a1 = fmaf(whh[1][4*i+1], hv.y, a1);
          a1 = fmaf(whh[1][4*i+2], hv.z, a1); a1 = fmaf(whh[1][4*i+3], hv.w, a1);
          a2 = fmaf(whh[2][4*i+0], hv.x, a2); a2 = fmaf(whh[2][4*i+1], hv.y, a2);
          a2 = fmaf(whh[2][4*i+2], hv.z, a2); a2 = fmaf(whh[2][4*i+3], hv.w, a2);
        }
        acc[0][b4] = a0; acc[1][b4] = a1; acc[2][b4] = a2;
      }
      // reduce the 4 kl sub-chunks in-register, one masked store per combo
#pragma unroll
      for (int gi = 0; gi < 3; ++gi)
#pragma unroll
        for (int b4 = 0; b4 < 4; ++b4) {
          float v = acc[gi][b4];
          v += __shfl_xor(v, 16, 64);
          v += __shfl_xor(v, 32, 64);
          if (l < 16)
            part[((gi * 8 + pass * 4 + b4) * 8 + w) * 17 + jj] = v;
        }
    }

    // ---- stage x(t+1) (consumed at t+1 after this step's (B)) ----------
    if (t + 1 < Tt) {
      const int bl = tid >> 6, k4 = (tid & 63) * 4;
      *(float4*)(x_tile + ((t + 1) & 1) * 8 * II + bl * II + k4) =
          *(const float4*)(x + ((size_t)(b0 + bl) * Tt + (t + 1)) * II + k4);
    }
    __syncthreads();  // (B) partials + x(t+1) visible; h_tile reads done

    // ---- reduce + elementwise + tagged h store (threads 0..127) --------
    if (tid < 128) {
      const int jr = tid & 15, br = tid >> 4;
      float s0 = bia0, s1 = bia1, s2 = bia2;
#pragma unroll
      for (int ww = 0; ww < 8; ++ww) {
        s0 += part[((0 * 8 + br) * 8 + ww) * 17 + jr];
        s1 += part[((1 * 8 + br) * 8 + ww) * 17 + jr];
        s2 += part[((2 * 8 + br) * 8 + ww) * 17 + jr];
      }
      const float tf = (float)t;
      const float r  = 1.0f / (1.0f + __expf(-s0));
      const float o  = 1.0f / (1.0f + __expf(-s1));
      const float gg = 1.0f - 2.0f / (1.0f + __expf(2.0f * s2));
      const float kn = r * (tf - EPSc) + (1.0f - r) * k_st;
      const float d  = tf - kn;
      const float f  = __expf(PV * __logf((d + EPSc) / (d + 1.0f)));
      const float cn = f * c_st + (1.0f - f) * gg;
      const float hn = o * (1.0f - 2.0f / (1.0f + __expf(2.0f * cn)));
      c_st = cn; k_st = kn;

      // data+signal fused: one relaxed agent dwordx2, no drain, no flag
      if (t + 1 < Tt) {
        u64* hp = hbuf2 + (size_t)((t + 1) & 1) * Bb * Hh +
                  (size_t)(b0 + br) * Hh + j0 + jr;
        u64 atom = ((u64)(unsigned)(t + 1) << 32) |
                   (u64)__float_as_uint(hn);
        __hip_atomic_store(hp, atom, __ATOMIC_RELAXED,
                           __HIP_MEMORY_SCOPE_AGENT);
      }

      // out[] store (plain, cached; off every critical path)
      const int b = b0 + br, j = j0 + jr;
      out[((size_t)b * Tt + t) * Hh + j] = hn;
      if (t == Tt - 1) {
        const size_t base = (size_t)Bb * Tt * Hh;
        out[base + 0 * Bb * Hh + (size_t)b * Hh + j] = hn;  // h_f
        out[base + 1 * Bb * Hh + (size_t)b * Hh + j] = cn;  // c_f
        out[base + 2 * Bb * Hh + (size_t)b * Hh + j] = kn;  // k_f
      }
    }
    // no (C)/(D): next iteration's poll self-synchronizes on the tags
  }
  (void)broken;
}

extern "C" void kernel_launch(void* const* d_in, const int* in_sizes, int n_in,
                              void* d_out, int out_size, void* d_ws, size_t ws_size,
                              hipStream_t stream) {
  const float* x    = (const float*)d_in[0];
  const float* Wih  = (const float*)d_in[1];
  const float* Whh  = (const float*)d_in[2];
  const float* bias = (const float*)d_in[3];
  float* out = (float*)d_out;

  u64* hbuf2 = (u64*)d_ws;  // [2][64][512] u64 = 512 KiB

  plr_init<<<32, 1024, 0, stream>>>(hbuf2);
  plr_main<<<256, 512, 0, stream>>>(x, Wih, Whh, bias, out, hbuf2);
}

// Round 4
// 5619.929 us; speedup vs baseline: 121.3958x; 1.0286x over previous
//
#include <hip/hip_runtime.h>
#include <stdint.h>
#include <stddef.h>

// PowerLawLayer RNN, MI355X persistent-kernel, R8.
//
// R4: 19.7 ms; latency-bound (VALUBusy 11.6%, HBM 1.3%).
// R5: flag-store barrier: NEUTRAL => barrier mechanics not the cost.
// R6: sc0 "XCD-local" exchange: CATASTROPHIC (682 ms). sc0 has NO cross-CU
//     visibility on gfx950; agent (sc1->LLC) is the only coherence point.
// R7: tagged dataflow (tag<<32|f32 atoms, poll data itself): 5.78 ms
//     (3.5x). VALUBusy 42.8%. 5.65 us/step vs 0.96 us FMA floor.
// R8: wave-decoupled dataflow. Wave w's h-gemv only reads h cols
//     [64w,64w+64) (kc in [4w,4w+4)) => only 4 producer WGs feed it.
//     Make everything wave-private: per-wave poll (lane l <-> col 64w+l),
//     per-wave h_tile stripe fill, per-wave x k-window [32w,32w+32) stage.
//     Same-wave LDS ops are in-order => no barrier for any of it.
//     Only cross-wave structure: part[] partial sums => ONE
//     __syncthreads/step, part[] double-buffered.
//     WAR proof: writes to part[t&1] at step t+2 occur after B(t+1);
//     updater reads of part[t&1] (step t) complete before the updater
//     arrives at B(t+1). Barriers/step: 3 -> 1. Straggler set per wave:
//     32 -> 4 producers. Updater tail (waves 0-1) overlaps other waves'
//     poll/x-part of step t+1.
//
// Workspace: hbuf2[2][64][512] u64 = 524,288 B.

#define Hh   512
#define Tt   1024
#define Bb   64
#define II   256
#define EPSc 0.001f
#define PV   0.2f

typedef unsigned long long u64;

__global__ __launch_bounds__(1024) void plr_init(u64* hbuf2) {
  // buf0: tag 0 == "h(0) ready" (bits = 0.0f). buf1: tag 0 != 1 => stale.
  int idx = blockIdx.x * blockDim.x + threadIdx.x;
  hbuf2[idx] = 0ull;
  hbuf2[idx + 32768] = 0ull;
}

__global__ __launch_bounds__(512, 2)
void plr_main(
    const float* __restrict__ x,    // [B, T, I]
    const float* __restrict__ Wih,  // [3H, I]
    const float* __restrict__ Whh,  // [3H, H]
    const float* __restrict__ bias, // [3H]
    float* __restrict__ out,        // [B,T,H] ++ h_f ++ c_f ++ k_f
    u64* hbuf2)                     // [2][B][H] tagged h atoms
{
  __shared__ float h_tile[8 * Hh];        // [bl][j']        16 KB
  __shared__ float x_tile[2 * 8 * II];    // [buf][bl][k]    16 KB
  __shared__ float part[2 * 3264];        // [pb]((gi*8+bl)*8+w)*17+jj 25.5 KB

  const int tid = threadIdx.x;
  const int w   = tid >> 6;          // wave 0..7
  const int l   = tid & 63;
  const int jj  = l & 15;            // weight row within slice
  const int kc  = (w << 2) | ((l >> 4) & 3);  // k-chunk 0..31
  const int bid = blockIdx.x;
  const int g   = bid & 7;           // batch group
  const int s   = bid >> 3;          // hidden slice 0..31
  const int j0  = s * 16;
  const int b0  = g * 8;
  // wave-private windows
  const int jw  = w << 6;            // h cols [jw, jw+64) consumed by wave w
  const int bls = l >> 3;            // staging batch (x)
  const int xk  = (w << 5) + (l & 7) * 4;  // x col window [32w,32w+32)

  // ---- one-time: weights into registers (72 floats/thread) ------------
  float whh[3][16];
  float wih[3][8];
#pragma unroll
  for (int gi = 0; gi < 3; ++gi) {
    const int row = gi * Hh + j0 + jj;
    const float4* ph = (const float4*)(Whh + (size_t)row * Hh + kc * 16);
#pragma unroll
    for (int i = 0; i < 4; ++i) {
      float4 v = ph[i];
      whh[gi][4*i+0] = v.x; whh[gi][4*i+1] = v.y;
      whh[gi][4*i+2] = v.z; whh[gi][4*i+3] = v.w;
    }
    const float4* pi = (const float4*)(Wih + (size_t)row * II + kc * 8);
#pragma unroll
    for (int i = 0; i < 2; ++i) {
      float4 v = pi[i];
      wih[gi][4*i+0] = v.x; wih[gi][4*i+1] = v.y;
      wih[gi][4*i+2] = v.z; wih[gi][4*i+3] = v.w;
    }
  }

  // ---- updater state (threads 0..127: br = tid>>4, jr = tid&15) -------
  float c_st = 0.0f, k_st = -1.0f;
  float bia0 = 0.f, bia1 = 0.f, bia2 = 0.f;
  if (tid < 128) {
    const int jr = tid & 15;
    bia0 = bias[0 * Hh + j0 + jr];
    bia1 = bias[1 * Hh + j0 + jr];
    bia2 = bias[2 * Hh + j0 + jr];
  }

  // ---- prologue: stage x(0), wave-private window (no barrier) ---------
  *(float4*)(x_tile + bls * II + xk) =
      *(const float4*)(x + ((size_t)(b0 + bls) * Tt + 0) * II + xk);

  bool broken = false;  // bounded-spin escape (never taken when co-resident)

  for (int t = 0; t < Tt; ++t) {
    // ---- issue tagged h loads: lane l owns col jw+l, 8 batches ---------
    const u64* hb = hbuf2 + (size_t)(t & 1) * Bb * Hh + (size_t)b0 * Hh;
    u64 got[8];
#pragma unroll
    for (int i = 0; i < 8; ++i)
      got[i] = __hip_atomic_load(hb + (size_t)i * Hh + jw + l,
                                 __ATOMIC_RELAXED, __HIP_MEMORY_SCOPE_AGENT);

    // ---- overlap: x-part gemv (h-independent, wave-private x window) ---
    const float* xt = x_tile + (t & 1) * 8 * II;
    float xacc[3][8];
#pragma unroll
    for (int bl = 0; bl < 8; ++bl) {
      const float4* x4 = (const float4*)(xt + bl * II) + kc * 2;
      float a0 = 0.f, a1 = 0.f, a2 = 0.f;
#pragma unroll
      for (int i = 0; i < 2; ++i) {
        float4 xv = x4[i];
        a0 = fmaf(wih[0][4*i+0], xv.x, a0); a0 = fmaf(wih[0][4*i+1], xv.y, a0);
        a0 = fmaf(wih[0][4*i+2], xv.z, a0); a0 = fmaf(wih[0][4*i+3], xv.w, a0);
        a1 = fmaf(wih[1][4*i+0], xv.x, a1); a1 = fmaf(wih[1][4*i+1], xv.y, a1);
        a1 = fmaf(wih[1][4*i+2], xv.z, a1); a1 = fmaf(wih[1][4*i+3], xv.w, a1);
        a2 = fmaf(wih[2][4*i+0], xv.x, a2); a2 = fmaf(wih[2][4*i+1], xv.y, a2);
        a2 = fmaf(wih[2][4*i+2], xv.z, a2); a2 = fmaf(wih[2][4*i+3], xv.w, a2);
      }
      xacc[0][bl] = a0; xacc[1][bl] = a1; xacc[2][bl] = a2;
    }

    // ---- retry: wave-local, gated only on this wave's 4 producers ------
    {
      const unsigned want = (unsigned)t;
      int it = 0;
      for (;;) {
        bool ok = true;
#pragma unroll
        for (int i = 0; i < 8; ++i) ok &= ((unsigned)(got[i] >> 32) == want);
        if (__all((int)ok)) break;          // wave-coherent exit
        if (++it > (1 << 20)) { broken = true; break; }
        __builtin_amdgcn_s_sleep(1);
#pragma unroll
        for (int i = 0; i < 8; ++i)
          if ((unsigned)(got[i] >> 32) != want)
            got[i] = __hip_atomic_load(hb + (size_t)i * Hh + jw + l,
                                       __ATOMIC_RELAXED,
                                       __HIP_MEMORY_SCOPE_AGENT);
      }
    }

    // ---- fill this wave's h_tile stripe (same-wave LDS is in-order) ----
#pragma unroll
    for (int i = 0; i < 8; ++i)
      h_tile[i * Hh + jw + l] = __uint_as_float((unsigned)got[i]);

    // ---- h-part gemv: reads only cols [jw, jw+64) => no barrier --------
    float* pb = part + (t & 1) * 3264;
#pragma unroll
    for (int pass = 0; pass < 2; ++pass) {
      float acc[3][4];
#pragma unroll
      for (int b4 = 0; b4 < 4; ++b4) {
        const int bl = pass * 4 + b4;
        const float4* h4 = (const float4*)(h_tile + bl * Hh) + kc * 4;
        float a0 = xacc[0][bl], a1 = xacc[1][bl], a2 = xacc[2][bl];
#pragma unroll
        for (int i = 0; i < 4; ++i) {
          float4 hv = h4[i];
          a0 = fmaf(whh[0][4*i+0], hv.x, a0); a0 = fmaf(whh[0][4*i+1], hv.y, a0);
          a0 = fmaf(whh[0][4*i+2], hv.z, a0); a0 = fmaf(whh[0][4*i+3], hv.w, a0);
          a1 = fmaf(whh[1][4*i+0], hv.x, a1); a1 = fmaf(whh[1][4*i+1], hv.y, a1);
          a1 = fmaf(whh[1][4*i+2], hv.z, a1); a1 = fmaf(whh[1][4*i+3], hv.w, a1);
          a2 = fmaf(whh[2][4*i+0], hv.x, a2); a2 = fmaf(whh[2][4*i+1], hv.y, a2);
          a2 = fmaf(whh[2][4*i+2], hv.z, a2); a2 = fmaf(whh[2][4*i+3], hv.w, a2);
        }
        acc[0][b4] = a0; acc[1][b4] = a1; acc[2][b4] = a2;
      }
      // reduce the 4 kl sub-chunks in-register, one masked store per combo
#pragma unroll
      for (int gi = 0; gi < 3; ++gi)
#pragma unroll
        for (int b4 = 0; b4 < 4; ++b4) {
          float v = acc[gi][b4];
          v += __shfl_xor(v, 16, 64);
          v += __shfl_xor(v, 32, 64);
          if (l < 16)
            pb[((gi * 8 + pass * 4 + b4) * 8 + w) * 17 + jj] = v;
        }
    }

    // ---- stage x(t+1), wave-private window -----------------------------
    if (t + 1 < Tt)
      *(float4*)(x_tile + ((t + 1) & 1) * 8 * II + bls * II + xk) =
          *(const float4*)(x + ((size_t)(b0 + bls) * Tt + (t + 1)) * II + xk);

    __syncthreads();  // (B) the ONE barrier: partials visible to updaters

    // ---- reduce + elementwise + tagged h store (waves 0-1 only) --------
    // Other waves loop immediately: poll(t+1) overlaps this tail.
    if (tid < 128) {
      const int jr = tid & 15, br = tid >> 4;
      float s0 = bia0, s1 = bia1, s2 = bia2;
#pragma unroll
      for (int ww = 0; ww < 8; ++ww) {
        s0 += pb[((0 * 8 + br) * 8 + ww) * 17 + jr];
        s1 += pb[((1 * 8 + br) * 8 + ww) * 17 + jr];
        s2 += pb[((2 * 8 + br) * 8 + ww) * 17 + jr];
      }
      const float tf = (float)t;
      const float r  = 1.0f / (1.0f + __expf(-s0));
      const float o  = 1.0f / (1.0f + __expf(-s1));
      const float gg = 1.0f - 2.0f / (1.0f + __expf(2.0f * s2));
      const float kn = r * (tf - EPSc) + (1.0f - r) * k_st;
      const float d  = tf - kn;
      const float f  = __expf(PV * __logf((d + EPSc) / (d + 1.0f)));
      const float cn = f * c_st + (1.0f - f) * gg;
      const float hn = o * (1.0f - 2.0f / (1.0f + __expf(2.0f * cn)));
      c_st = cn; k_st = kn;

      // data+signal fused: one relaxed agent dwordx2
      if (t + 1 < Tt) {
        u64* hp = hbuf2 + (size_t)((t + 1) & 1) * Bb * Hh +
                  (size_t)(b0 + br) * Hh + j0 + jr;
        u64 atom = ((u64)(unsigned)(t + 1) << 32) |
                   (u64)__float_as_uint(hn);
        __hip_atomic_store(hp, atom, __ATOMIC_RELAXED,
                           __HIP_MEMORY_SCOPE_AGENT);
      }

      // out[] store (plain, cached; off every critical path)
      const int b = b0 + br, j = j0 + jr;
      out[((size_t)b * Tt + t) * Hh + j] = hn;
      if (t == Tt - 1) {
        const size_t base = (size_t)Bb * Tt * Hh;
        out[base + 0 * Bb * Hh + (size_t)b * Hh + j] = hn;  // h_f
        out[base + 1 * Bb * Hh + (size_t)b * Hh + j] = cn;  // c_f
        out[base + 2 * Bb * Hh + (size_t)b * Hh + j] = kn;  // k_f
      }
    }
    // no second barrier: part[] is double-buffered; next write to this
    // buffer (step t+2) is ordered after B(t+1), which the updater only
    // reaches after its reads above complete.
  }
  (void)broken;
}

extern "C" void kernel_launch(void* const* d_in, const int* in_sizes, int n_in,
                              void* d_out, int out_size, void* d_ws, size_t ws_size,
                              hipStream_t stream) {
  const float* x    = (const float*)d_in[0];
  const float* Wih  = (const float*)d_in[1];
  const float* Whh  = (const float*)d_in[2];
  const float* bias = (const float*)d_in[3];
  float* out = (float*)d_out;

  u64* hbuf2 = (u64*)d_ws;  // [2][64][512] u64 = 512 KiB

  plr_init<<<32, 1024, 0, stream>>>(hbuf2);
  plr_main<<<256, 512, 0, stream>>>(x, Wih, Whh, bias, out, hbuf2);
}